// Round 1
// baseline (18205.634 us; speedup 1.0000x reference)
//
#include <hip/hip_runtime.h>
#include <hip/hip_cooperative_groups.h>

namespace cg = cooperative_groups;

typedef __attribute__((ext_vector_type(8))) short bf16x8;   // 8 bf16 in 4 VGPRs
typedef __attribute__((ext_vector_type(4))) float f32x4;

#define NB 256   // batch
#define NTT 512  // time steps
#define NH 512   // hidden
#define NIN 9
#define NO 3

__device__ __forceinline__ short f2bf(float f) {  // RNE fp32 -> bf16
  unsigned u = __builtin_bit_cast(unsigned, f);
  u = (u + 0x7fffu + ((u >> 16) & 1u)) >> 16;
  return (short)u;
}
__device__ __forceinline__ float bf2f(short s) {
  unsigned u = ((unsigned)(unsigned short)s) << 16;
  return __builtin_bit_cast(float, u);
}
__device__ __forceinline__ float sigf(float x) { return 1.f / (1.f + __expf(-x)); }
__device__ __forceinline__ float tanh_fast(float x) { return 1.f - 2.f / (1.f + __expf(2.f * x)); }

// Grid: 256 WGs x 256 threads, persistent, one grid.sync per timestep.
// WG = (batch block of 64) x (h block of 8 -> 32 gate cols).
// Per-wave K-split (128 each); W_hh/W_fc slices live in registers as hi/lo bf16.
__global__ __launch_bounds__(256) void lstm_kernel(
    const float* __restrict__ x, const float* __restrict__ W_ih,
    const float* __restrict__ W_hh, const float* __restrict__ b_ih,
    const float* __restrict__ b_hh, const float* __restrict__ W_fc,
    const float* __restrict__ b_fc, const int* __restrict__ horizon,
    float* __restrict__ out, short* __restrict__ ws) {
  const int tid  = threadIdx.x;
  const int bid  = blockIdx.x;
  const int mb   = bid & 3;    // batch block — XCD-affine (bid%8 round-robin => one A-slab per XCD)
  const int hb   = bid >> 2;   // h block 0..63
  const int mbase = mb * 64;
  const int hbase = hb * 8;
  const int wid  = tid >> 6;   // wave id = K-split id = h-quad for epilogue
  const int lane = tid & 63;
  const int l15  = lane & 15;
  const int quad = lane >> 4;
  const int b_l  = tid & 63;   // batch row owned in epilogue
  const int q    = tid >> 6;
  const int b_g  = mbase + b_l;

  short* buf0 = ws;            // hx double buffers, bf16 [256][512]
  short* buf1 = ws + NB * NH;

  __shared__ __align__(16) float part[4][48][68];  // [wave][48 cols: 32 gates + 16 fc-pad][64 b + pad]
  __shared__ float Wih_l[32][NIN];
  __shared__ float bsum[32];
  __shared__ __align__(16) short hstage[64][8];

  const int hor = *horizon;
  const float bfc0 = b_fc[0], bfc1 = b_fc[1], bfc2 = b_fc[2];

  // ---- one-time: build persistent B fragments (hi/lo split) ----
  // B[k][n] layout per lane: n = l15, k = quad*8 + j  (16x16x32 bf16 MFMA)
  bf16x8 Bhi[3][4], Blo[3][4];  // [ntile: 2 gate tiles + 1 fc tile][kt within this wave's 128-K]
#pragma unroll
  for (int nt = 0; nt < 3; ++nt)
#pragma unroll
    for (int kt = 0; kt < 4; ++kt) {
      bf16x8 vh, vl;
#pragma unroll
      for (int j = 0; j < 8; ++j) {
        int k = wid * 128 + kt * 32 + quad * 8 + j;
        float v;
        if (nt < 2) {
          int c  = nt * 16 + l15;                       // local gate col 0..31 = [i8|f8|g8|o8]
          int gr = (c >> 3) * NH + hbase + (c & 7);     // global gate row
          v = W_hh[(size_t)gr * NH + k];
        } else {
          v = (l15 < NO) ? W_fc[(size_t)l15 * NH + k] : 0.f;
        }
        short hi = f2bf(v);
        short lo = f2bf(v - bf2f(hi));
        vh[j] = hi; vl[j] = lo;
      }
      Bhi[nt][kt] = vh; Blo[nt][kt] = vl;
    }

  if (tid < 32) {
    int gr = (tid >> 3) * NH + hbase + (tid & 7);
    bsum[tid] = b_ih[gr] + b_hh[gr];
#pragma unroll
    for (int k = 0; k < NIN; ++k) Wih_l[tid][k] = W_ih[gr * NIN + k];
  }
  if (tid < 64) {  // zero our slab of buf0 (h_0 = 0); d_ws is poisoned by harness
    f32x4 z = {0.f, 0.f, 0.f, 0.f};
    *(f32x4*)(buf0 + (size_t)(mbase + tid) * NH + hbase) = z;
  }

  float cst[2] = {0.f, 0.f};  // cell state: rows b_l, h = q and q+4
  int tmod = 0;

  cg::grid_group grid = cg::this_grid();
  grid.sync();

  for (int t = 0; t <= NTT; ++t) {
    const short* cur = (t & 1) ? buf1 : buf0;
    short* nxt       = (t & 1) ? buf0 : buf1;

    // prefetch this step's x row early (hides L2/LLC latency behind MFMA)
    float xin[NIN];
    if (t < NTT) {
      const float* xr = x + ((size_t)b_g * NTT + t) * NIN;
#pragma unroll
      for (int k = 0; k < NIN; ++k) xin[k] = xr[k];
    }

    // ---- MFMA: partial gates (+fc cols) over this wave's K range ----
    f32x4 zero4 = {0.f, 0.f, 0.f, 0.f};
    f32x4 acc[4][3];
#pragma unroll
    for (int mt = 0; mt < 4; ++mt)
#pragma unroll
      for (int nt = 0; nt < 3; ++nt) acc[mt][nt] = zero4;

#pragma unroll
    for (int kt = 0; kt < 4; ++kt) {
#pragma unroll
      for (int mt = 0; mt < 4; ++mt) {
        bf16x8 a = *(const bf16x8*)(cur + (size_t)(mbase + mt * 16 + l15) * NH +
                                    wid * 128 + kt * 32 + quad * 8);
#pragma unroll
        for (int nt = 0; nt < 3; ++nt) {
          acc[mt][nt] = __builtin_amdgcn_mfma_f32_16x16x32_bf16(a, Bhi[nt][kt], acc[mt][nt], 0, 0, 0);
          acc[mt][nt] = __builtin_amdgcn_mfma_f32_16x16x32_bf16(a, Blo[nt][kt], acc[mt][nt], 0, 0, 0);
        }
      }
    }

    // D layout: row(m) = quad*4 + reg, col(n) = l15  -> 4 consecutive b => b128 store
#pragma unroll
    for (int mt = 0; mt < 4; ++mt)
#pragma unroll
      for (int nt = 0; nt < 3; ++nt)
        *(f32x4*)&part[wid][nt * 16 + l15][mt * 16 + quad * 4] = acc[mt][nt];
    __syncthreads();

    // ---- reduce fc cols: out_{t-1} = fc(h_t) ----
    float o0 = bfc0, o1 = bfc1, o2 = bfc2;
#pragma unroll
    for (int w = 0; w < 4; ++w) {
      o0 += part[w][32][b_l];
      o1 += part[w][33][b_l];
      o2 += part[w][34][b_l];
    }
    if (t > 0 && hb == 0 && q == 0) {
      float* po = out + ((size_t)b_g * NTT + (t - 1)) * NO;
      po[0] = o0; po[1] = o1; po[2] = o2;
    }
    if (t == NTT) break;

    const bool raw = (t < 5) || (tmod == 0);
    if (!raw) { xin[0] = o0; xin[1] = o1; xin[2] = o2; }

    // ---- reduce gates, add x-path (fp32 exact), cell update ----
#pragma unroll
    for (int e = 0; e < 2; ++e) {
      const int h_l = q + 4 * e;
      float gv[4];
#pragma unroll
      for (int g4 = 0; g4 < 4; ++g4) {
        const int c = g4 * 8 + h_l;
        float s = bsum[c];
#pragma unroll
        for (int w = 0; w < 4; ++w) s += part[w][c][b_l];
#pragma unroll
        for (int k = 0; k < NIN; ++k) s += xin[k] * Wih_l[c][k];
        gv[g4] = s;
      }
      const float cn = sigf(gv[1]) * cst[e] + sigf(gv[0]) * tanh_fast(gv[2]);
      cst[e] = cn;
      const float hn = sigf(gv[3]) * tanh_fast(cn);
      hstage[b_l][h_l] = f2bf(hn);
    }
    __syncthreads();
    if (tid < 64) {  // 16B rows -> coalesced-enough slab write
      *(f32x4*)(nxt + (size_t)(mbase + tid) * NH + hbase) = *(f32x4*)&hstage[tid][0];
    }
    ++tmod; if (tmod == hor) tmod = 0;
    grid.sync();
  }
}

extern "C" void kernel_launch(void* const* d_in, const int* in_sizes, int n_in,
                              void* d_out, int out_size, void* d_ws, size_t ws_size,
                              hipStream_t stream) {
  const float* x    = (const float*)d_in[0];
  const float* W_ih = (const float*)d_in[1];
  const float* W_hh = (const float*)d_in[2];
  const float* b_ih = (const float*)d_in[3];
  const float* b_hh = (const float*)d_in[4];
  const float* W_fc = (const float*)d_in[5];
  const float* b_fc = (const float*)d_in[6];
  const int*   hor  = (const int*)d_in[7];
  float* outp = (float*)d_out;
  short* ws   = (short*)d_ws;  // 2 x [256][512] bf16 = 512 KB
  void* args[] = {&x, &W_ih, &W_hh, &b_ih, &b_hh, &W_fc, &b_fc, &hor, &outp, &ws};
  hipLaunchCooperativeKernel(lstm_kernel, dim3(256), dim3(256), args, 0, stream);
}

// Round 3
// 6144.226 us; speedup vs baseline: 2.9630x; 2.9630x over previous
//
#include <hip/hip_runtime.h>

typedef __attribute__((ext_vector_type(8))) short bf16x8;   // 8 bf16 in 4 VGPRs
typedef __attribute__((ext_vector_type(4))) float f32x4;

#define NTT 512
#define NH  512
#define NIN 9
#define NO  3
#define GROUPS  8     // batch groups
#define MEMBERS 32    // WGs per group
#define MROWS   32    // batch rows per group
#define HPW     16    // hidden units per WG

__device__ __forceinline__ short f2bf(float f) {  // RNE fp32 -> bf16
  unsigned u = __builtin_bit_cast(unsigned, f);
  u = (u + 0x7fffu + ((u >> 16) & 1u)) >> 16;
  return (short)u;
}
__device__ __forceinline__ float bf2f(short s) {
  unsigned u = ((unsigned)(unsigned short)s) << 16;
  return __builtin_bit_cast(float, u);
}
__device__ __forceinline__ float sigf(float x) { return 1.f / (1.f + __expf(-x)); }
__device__ __forceinline__ float tanh_fast(float x) { return 1.f - 2.f / (1.f + __expf(2.f * x)); }

// 256 WGs = 8 groups (32 batch rows) x 32 members (16 hidden each). Plain
// launch, no cooperative API. Per-group sync via monotonic signed step flags
// at agent scope (0xAA poison is negative -> no init needed). W_hh/W_fc slices
// persistent in registers as hi/lo bf16 (fp32-exact weights); only h crosses
// WGs, as bf16 through the LLC.
__global__ __launch_bounds__(256, 1) void lstm_kernel(
    const float* __restrict__ x, const float* __restrict__ W_ih,
    const float* __restrict__ W_hh, const float* __restrict__ b_ih,
    const float* __restrict__ b_hh, const float* __restrict__ W_fc,
    const float* __restrict__ b_fc, const int* __restrict__ horizon,
    float* __restrict__ out, unsigned short* __restrict__ ws) {
  const int tid  = threadIdx.x;
  const int bid  = blockIdx.x;
  const int g    = bid >> 5;   // group: batch rows [32g, 32g+32)
  const int w    = bid & 31;   // member: hidden [16w, 16w+16)
  const int wid  = tid >> 6;   // wave = gate index (i,f,g,o)
  const int lane = tid & 63;
  const int l15  = lane & 15;
  const int quad = lane >> 4;
  const int hl   = tid & 15;   // update mapping: hidden-local
  const int b0   = tid >> 4;   // update mapping: rows b0, b0+16

  // ws (u16): h dbuf [2][8 grp][32 rows][512] = 2*131072 u16 = 512 KB; flags after.
  unsigned short* buf0 = ws;
  unsigned short* buf1 = ws + 131072;
  int* fl = (int*)(ws + 262144) + g * MEMBERS;   // 32 ints per group

  __shared__ __align__(16) unsigned short hbuf[32][520];  // 65*16B rows: aligned b128
  __shared__ __align__(16) float gbuf[4][16][36];         // [gate][hl][b] stride 144B
  __shared__ float fcbuf[4][32][4];                       // [wave(K-split)][b][o]
  __shared__ float xbuf[32][NIN];
  __shared__ float xw[64][NIN];                           // W_ih rows (gate*16+hl)
  __shared__ float bsl[64];

  // ---- persistent B fragments: W_hh hi/lo, full K, gate 'wid', n=l15 ----
  bf16x8 Bhi[16], Blo[16];
#pragma unroll
  for (int kt = 0; kt < 16; ++kt) {
    bf16x8 vh, vl;
    const int row = wid * NH + w * HPW + l15;
#pragma unroll
    for (int j = 0; j < 8; ++j) {
      int k = kt * 32 + quad * 8 + j;
      float v = W_hh[(size_t)row * NH + k];
      short hi = f2bf(v);
      vh[j] = hi; vl[j] = f2bf(v - bf2f(hi));
    }
    Bhi[kt] = vh; Blo[kt] = vl;
  }
  // fc tile: wave wid covers K quarter [128*wid, +128)
  bf16x8 Fhi[4], Flo[4];
#pragma unroll
  for (int kk = 0; kk < 4; ++kk) {
    bf16x8 vh, vl;
#pragma unroll
    for (int j = 0; j < 8; ++j) {
      int k = (wid * 4 + kk) * 32 + quad * 8 + j;
      float v = (l15 < NO) ? W_fc[(size_t)l15 * NH + k] : 0.f;
      short hi = f2bf(v);
      vh[j] = hi; vl[j] = f2bf(v - bf2f(hi));
    }
    Fhi[kk] = vh; Flo[kk] = vl;
  }
  if (tid < 64) {  // x-path weights + biases, fp32 exact, in LDS
    int grow = (tid >> 4) * NH + w * HPW + (tid & 15);
    bsl[tid] = b_ih[grow] + b_hh[grow];
#pragma unroll
    for (int k = 0; k < NIN; ++k) xw[tid][k] = W_ih[grow * NIN + k];
  }
  for (int i = tid; i < 8320; i += 256) ((unsigned*)hbuf)[i] = 0u;  // h_0 = 0
  const float bfc0 = b_fc[0], bfc1 = b_fc[1], bfc2 = b_fc[2];
  const int hor = *horizon;
  __syncthreads();

  float cst[2] = {0.f, 0.f};
  int tmod = 0;

  for (int t = 0; t <= NTT; ++t) {
    // x_t slice for the group -> LDS (read-only global data, plain loads)
    if (t < NTT) {
      for (int i = tid; i < MROWS * NIN; i += 256) {
        int r = i / NIN, k = i - r * NIN;
        xbuf[r][k] = x[((size_t)(g * MROWS + r) * NTT + t) * NIN + k];
      }
    }

    // ---- MFMA: this gate's 16 cols over full K, both M-tiles; fc K-quarter ----
    f32x4 z4 = {0.f, 0.f, 0.f, 0.f};
    f32x4 accg[2] = {z4, z4}, accf[2] = {z4, z4};
#pragma unroll
    for (int kt = 0; kt < 16; ++kt) {
      bf16x8 a0 = *(const bf16x8*)&hbuf[l15][kt * 32 + quad * 8];
      bf16x8 a1 = *(const bf16x8*)&hbuf[16 + l15][kt * 32 + quad * 8];
      accg[0] = __builtin_amdgcn_mfma_f32_16x16x32_bf16(a0, Bhi[kt], accg[0], 0, 0, 0);
      accg[1] = __builtin_amdgcn_mfma_f32_16x16x32_bf16(a1, Bhi[kt], accg[1], 0, 0, 0);
      accg[0] = __builtin_amdgcn_mfma_f32_16x16x32_bf16(a0, Blo[kt], accg[0], 0, 0, 0);
      accg[1] = __builtin_amdgcn_mfma_f32_16x16x32_bf16(a1, Blo[kt], accg[1], 0, 0, 0);
      if ((kt >> 2) == wid) {
        int kk = kt & 3;
        accf[0] = __builtin_amdgcn_mfma_f32_16x16x32_bf16(a0, Fhi[kk], accf[0], 0, 0, 0);
        accf[1] = __builtin_amdgcn_mfma_f32_16x16x32_bf16(a1, Fhi[kk], accf[1], 0, 0, 0);
        accf[0] = __builtin_amdgcn_mfma_f32_16x16x32_bf16(a0, Flo[kk], accf[0], 0, 0, 0);
        accf[1] = __builtin_amdgcn_mfma_f32_16x16x32_bf16(a1, Flo[kk], accf[1], 0, 0, 0);
      }
    }
    // D layout: row(b) = mt*16 + quad*4 + r, col = l15. 144B row stride: aligned.
#pragma unroll
    for (int mt = 0; mt < 2; ++mt)
      *(f32x4*)&gbuf[wid][l15][mt * 16 + quad * 4] = accg[mt];
    if (l15 < NO) {
#pragma unroll
      for (int mt = 0; mt < 2; ++mt)
#pragma unroll
        for (int r = 0; r < 4; ++r) fcbuf[wid][mt * 16 + quad * 4 + r][l15] = accf[mt][r];
    }
    __syncthreads();

    // out[t-1] = fc(h_t): member 0 writes (all members have identical sums)
    if (w == 0 && t > 0 && tid < MROWS * NO) {
      int b = tid / NO, o = tid - b * NO;
      float bo = (o == 0) ? bfc0 : (o == 1) ? bfc1 : bfc2;
      float ov = bo + fcbuf[0][b][o] + fcbuf[1][b][o] + fcbuf[2][b][o] + fcbuf[3][b][o];
      out[((size_t)(g * MROWS + b) * NTT + (t - 1)) * NO + o] = ov;
    }
    if (t == NTT) break;

    const bool raw = (t < 5) || (tmod == 0);
    unsigned* nxt32 = (unsigned*)(((t & 1) ? buf1 : buf0) + (size_t)g * (MROWS * NH));

    // ---- cell update: thread owns (b0, hl) and (b0+16, hl) ----
#pragma unroll
    for (int e = 0; e < 2; ++e) {
      int b = b0 + 16 * e;
      float xin[NIN];
#pragma unroll
      for (int k = 0; k < NIN; ++k) xin[k] = xbuf[b][k];
      if (!raw) {
        xin[0] = bfc0 + fcbuf[0][b][0] + fcbuf[1][b][0] + fcbuf[2][b][0] + fcbuf[3][b][0];
        xin[1] = bfc1 + fcbuf[0][b][1] + fcbuf[1][b][1] + fcbuf[2][b][1] + fcbuf[3][b][1];
        xin[2] = bfc2 + fcbuf[0][b][2] + fcbuf[1][b][2] + fcbuf[2][b][2] + fcbuf[3][b][2];
      }
      float gv[4];
#pragma unroll
      for (int gg = 0; gg < 4; ++gg) {
        int r = gg * 16 + hl;
        float s = bsl[r] + gbuf[gg][hl][b];
#pragma unroll
        for (int k = 0; k < NIN; ++k) s += xin[k] * xw[r][k];
        gv[gg] = s;
      }
      float cn = sigf(gv[1]) * cst[e] + sigf(gv[0]) * tanh_fast(gv[2]);
      cst[e] = cn;
      float hn = sigf(gv[3]) * tanh_fast(cn);
      // pack (hl even, hl odd) -> one u32 agent store straight to the LLC
      unsigned hb = (unsigned)(unsigned short)f2bf(hn);
      unsigned ob = (unsigned)__shfl_xor((int)hb, 1, 64);
      if (!(hl & 1))
        __hip_atomic_store(&nxt32[(size_t)b * 256 + w * 8 + (hl >> 1)], hb | (ob << 16),
                           __ATOMIC_RELAXED, __HIP_MEMORY_SCOPE_AGENT);
    }
    __syncthreads();  // per-wave s_waitcnt vmcnt(0) before s_barrier: stores at LLC

    // ---- group barrier: monotonic signed step flags; poison(<0) needs no init ----
    if (tid == 0)
      __hip_atomic_store(&fl[w], t + 1, __ATOMIC_RELEASE, __HIP_MEMORY_SCOPE_AGENT);
    if (tid < MEMBERS) {
      while (__hip_atomic_load(&fl[tid], __ATOMIC_ACQUIRE, __HIP_MEMORY_SCOPE_AGENT) < t + 1)
        __builtin_amdgcn_s_sleep(1);
    }
    __syncthreads();

    // ---- read group's h_{t+1} slab (32 KB) from LLC -> LDS ----
    const unsigned long long* src =
        (const unsigned long long*)(((t & 1) ? buf1 : buf0) + (size_t)g * (MROWS * NH));
#pragma unroll
    for (int j = 0; j < 16; ++j) {
      int idx = tid + 256 * j;  // 4096 u64 = 32 rows x 128
      unsigned long long v =
          __hip_atomic_load(src + idx, __ATOMIC_RELAXED, __HIP_MEMORY_SCOPE_AGENT);
      *(unsigned long long*)&hbuf[idx >> 7][(idx & 127) * 4] = v;
    }
    __syncthreads();
    ++tmod; if (tmod == hor) tmod = 0;
  }
}

extern "C" void kernel_launch(void* const* d_in, const int* in_sizes, int n_in,
                              void* d_out, int out_size, void* d_ws, size_t ws_size,
                              hipStream_t stream) {
  (void)in_sizes; (void)n_in; (void)out_size; (void)ws_size;
  const float* x    = (const float*)d_in[0];
  const float* W_ih = (const float*)d_in[1];
  const float* W_hh = (const float*)d_in[2];
  const float* b_ih = (const float*)d_in[3];
  const float* b_hh = (const float*)d_in[4];
  const float* W_fc = (const float*)d_in[5];
  const float* b_fc = (const float*)d_in[6];
  const int*   hor  = (const int*)d_in[7];
  lstm_kernel<<<dim3(256), dim3(256), 0, stream>>>(
      x, W_ih, W_hh, b_ih, b_hh, W_fc, b_fc, hor,
      (float*)d_out, (unsigned short*)d_ws);
}

// Round 4
// 4140.088 us; speedup vs baseline: 4.3974x; 1.4841x over previous
//
#include <hip/hip_runtime.h>

typedef __attribute__((ext_vector_type(8))) short bf16x8;   // 8 bf16 in 4 VGPRs
typedef __attribute__((ext_vector_type(4))) float f32x4;

#define NTT 512
#define NH  512
#define NIN 9
#define NO  3
#define GROUPS  8     // batch groups
#define MEMBERS 32    // WGs per group
#define MROWS   32    // batch rows per group
#define HPW     16    // hidden units per WG

__device__ __forceinline__ short f2bf(float f) {  // RNE fp32 -> bf16
  unsigned u = __builtin_bit_cast(unsigned, f);
  u = (u + 0x7fffu + ((u >> 16) & 1u)) >> 16;
  return (short)u;
}
__device__ __forceinline__ float bf2f(short s) {
  unsigned u = ((unsigned)(unsigned short)s) << 16;
  return __builtin_bit_cast(float, u);
}
__device__ __forceinline__ float sigf(float x) { return 1.f / (1.f + __expf(-x)); }
__device__ __forceinline__ float tanh_fast(float x) { return 1.f - 2.f / (1.f + __expf(2.f * x)); }

// 256 WGs = 8 groups (32 batch rows) x 32 members (16 hidden each).
// ALL cross-WG traffic (h slices + step flags) uses RELAXED agent-scope
// atomics: sc1 bit bypasses per-XCD L2 so data meets at the Infinity Cache;
// ordering comes from the per-wave s_waitcnt vmcnt(0) that __syncthreads
// implies before the flag store. No acquire/release -> no buffer_inv /
// buffer_wbl2 storms (round-3 killer: 548 MB FETCH of invalidate fallout).
__global__ __launch_bounds__(256, 1) void lstm_kernel(
    const float* __restrict__ x, const float* __restrict__ W_ih,
    const float* __restrict__ W_hh, const float* __restrict__ b_ih,
    const float* __restrict__ b_hh, const float* __restrict__ W_fc,
    const float* __restrict__ b_fc, const int* __restrict__ horizon,
    float* __restrict__ out, unsigned short* __restrict__ ws) {
  const int tid  = threadIdx.x;
  const int bid  = blockIdx.x;
  const int g    = bid >> 5;   // group: batch rows [32g, 32g+32)
  const int w    = bid & 31;   // member: hidden [16w, 16w+16)
  const int wid  = tid >> 6;   // wave = gate index (i,f,g,o)
  const int lane = tid & 63;
  const int l15  = lane & 15;
  const int quad = lane >> 4;
  const int hl   = tid & 15;   // update mapping: hidden-local
  const int b0   = tid >> 4;   // update mapping: rows b0, b0+16

  // ws (u16): h dbuf [2][8 grp][32 rows][512] = 512 KB; flags after.
  unsigned short* buf0 = ws;
  unsigned short* buf1 = ws + 131072;
  int* fl = (int*)(ws + 262144) + g * MEMBERS;   // 32 ints per group
  // monotonic signed flags: 0xAAAAAAAA poison < 1 -> no init, no grid sync

  __shared__ __align__(16) unsigned short hbuf[32][520];  // 1040B rows: b128-aligned
  __shared__ __align__(16) float gbuf[4][16][36];         // [gate][hl][b] 144B stride
  __shared__ float fcbuf[4][32][4];                       // [wave(K-split)][b][o]
  __shared__ float xbuf[32][NIN];
  __shared__ float xw[64][NIN];                           // W_ih rows (gate*16+hl)
  __shared__ float bsl[64];

  // ---- persistent B fragments: W_hh hi/lo (fp32-exact weights) ----
  bf16x8 Bhi[16], Blo[16];
#pragma unroll
  for (int kt = 0; kt < 16; ++kt) {
    bf16x8 vh, vl;
    const int row = wid * NH + w * HPW + l15;
#pragma unroll
    for (int j = 0; j < 8; ++j) {
      int k = kt * 32 + quad * 8 + j;
      float v = W_hh[(size_t)row * NH + k];
      short hi = f2bf(v);
      vh[j] = hi; vl[j] = f2bf(v - bf2f(hi));
    }
    Bhi[kt] = vh; Blo[kt] = vl;
  }
  // fc tile: wave wid covers K quarter [128*wid, +128)
  bf16x8 Fhi[4], Flo[4];
#pragma unroll
  for (int kk = 0; kk < 4; ++kk) {
    bf16x8 vh, vl;
#pragma unroll
    for (int j = 0; j < 8; ++j) {
      int k = (wid * 4 + kk) * 32 + quad * 8 + j;
      float v = (l15 < NO) ? W_fc[(size_t)l15 * NH + k] : 0.f;
      short hi = f2bf(v);
      vh[j] = hi; vl[j] = f2bf(v - bf2f(hi));
    }
    Fhi[kk] = vh; Flo[kk] = vl;
  }
  if (tid < 64) {  // x-path weights + biases, fp32 exact, in LDS
    int grow = (tid >> 4) * NH + w * HPW + (tid & 15);
    bsl[tid] = b_ih[grow] + b_hh[grow];
#pragma unroll
    for (int k = 0; k < NIN; ++k) xw[tid][k] = W_ih[grow * NIN + k];
  }
  for (int i = tid; i < 8320; i += 256) ((unsigned*)hbuf)[i] = 0u;  // h_0 = 0
  const float bfc0 = b_fc[0], bfc1 = b_fc[1], bfc2 = b_fc[2];
  const int hor = *horizon;
  __syncthreads();

  float cst[2] = {0.f, 0.f};
  int tmod = 0;

  for (int t = 0; t <= NTT; ++t) {
    // x_t slice: issue global loads NOW (regs), write LDS after MFMA so the
    // wave doesn't stall on vmcnt before the matrix work.
    float xv0 = 0.f, xv1 = 0.f;
    int r0 = 0, k0 = 0, r1 = 0, k1 = 0;
    if (t < NTT) {
      r0 = tid / NIN; k0 = tid - r0 * NIN;          // 256 of 288 elems
      if (r0 < MROWS) xv0 = x[((size_t)(g * MROWS + r0) * NTT + t) * NIN + k0];
      int i1 = tid + 256;                            // remaining 32
      r1 = i1 / NIN; k1 = i1 - r1 * NIN;
      if (i1 < MROWS * NIN) xv1 = x[((size_t)(g * MROWS + r1) * NTT + t) * NIN + k1];
    }

    // ---- MFMA: this gate's 16 cols over full K, both M-tiles; fc K-quarter ----
    f32x4 z4 = {0.f, 0.f, 0.f, 0.f};
    f32x4 accg[2] = {z4, z4}, accf[2] = {z4, z4};
#pragma unroll
    for (int kt = 0; kt < 16; ++kt) {
      bf16x8 a0 = *(const bf16x8*)&hbuf[l15][kt * 32 + quad * 8];
      bf16x8 a1 = *(const bf16x8*)&hbuf[16 + l15][kt * 32 + quad * 8];
      accg[0] = __builtin_amdgcn_mfma_f32_16x16x32_bf16(a0, Bhi[kt], accg[0], 0, 0, 0);
      accg[1] = __builtin_amdgcn_mfma_f32_16x16x32_bf16(a1, Bhi[kt], accg[1], 0, 0, 0);
      accg[0] = __builtin_amdgcn_mfma_f32_16x16x32_bf16(a0, Blo[kt], accg[0], 0, 0, 0);
      accg[1] = __builtin_amdgcn_mfma_f32_16x16x32_bf16(a1, Blo[kt], accg[1], 0, 0, 0);
      if ((kt >> 2) == wid) {
        int kk = kt & 3;
        accf[0] = __builtin_amdgcn_mfma_f32_16x16x32_bf16(a0, Fhi[kk], accf[0], 0, 0, 0);
        accf[1] = __builtin_amdgcn_mfma_f32_16x16x32_bf16(a1, Fhi[kk], accf[1], 0, 0, 0);
        accf[0] = __builtin_amdgcn_mfma_f32_16x16x32_bf16(a0, Flo[kk], accf[0], 0, 0, 0);
        accf[1] = __builtin_amdgcn_mfma_f32_16x16x32_bf16(a1, Flo[kk], accf[1], 0, 0, 0);
      }
    }
    // stage: D row(b) = mt*16 + quad*4 + r, col = l15
#pragma unroll
    for (int mt = 0; mt < 2; ++mt)
      *(f32x4*)&gbuf[wid][l15][mt * 16 + quad * 4] = accg[mt];
    if (l15 < NO) {
#pragma unroll
      for (int mt = 0; mt < 2; ++mt)
#pragma unroll
        for (int r = 0; r < 4; ++r) fcbuf[wid][mt * 16 + quad * 4 + r][l15] = accf[mt][r];
    }
    if (t < NTT) {
      if (r0 < MROWS) xbuf[r0][k0] = xv0;
      if (tid < MROWS * NIN - 256) xbuf[r1][k1] = xv1;
    }
    __syncthreads();

    if (t == NTT) {  // final fc only
      if (w == 0 && tid < MROWS * NO) {
        int b = tid / NO, o = tid - b * NO;
        float bo = (o == 0) ? bfc0 : (o == 1) ? bfc1 : bfc2;
        out[((size_t)(g * MROWS + b) * NTT + (t - 1)) * NO + o] =
            bo + fcbuf[0][b][o] + fcbuf[1][b][o] + fcbuf[2][b][o] + fcbuf[3][b][o];
      }
      break;
    }

    const bool raw = (t < 5) || (tmod == 0);
    unsigned long long* nxt64 =
        (unsigned long long*)(((t & 1) ? buf1 : buf0) + (size_t)g * (MROWS * NH));

    // ---- cell update: thread owns (b0, hl) and (b0+16, hl) ----
#pragma unroll
    for (int e = 0; e < 2; ++e) {
      int b = b0 + 16 * e;
      float xin[NIN];
#pragma unroll
      for (int k = 0; k < NIN; ++k) xin[k] = xbuf[b][k];
      if (!raw) {
        xin[0] = bfc0 + fcbuf[0][b][0] + fcbuf[1][b][0] + fcbuf[2][b][0] + fcbuf[3][b][0];
        xin[1] = bfc1 + fcbuf[0][b][1] + fcbuf[1][b][1] + fcbuf[2][b][1] + fcbuf[3][b][1];
        xin[2] = bfc2 + fcbuf[0][b][2] + fcbuf[1][b][2] + fcbuf[2][b][2] + fcbuf[3][b][2];
      }
      float gv[4];
#pragma unroll
      for (int gg = 0; gg < 4; ++gg) {
        int r = gg * 16 + hl;
        float s = bsl[r] + gbuf[gg][hl][b];
#pragma unroll
        for (int k = 0; k < NIN; ++k) s += xin[k] * xw[r][k];
        gv[gg] = s;
      }
      float cn = sigf(gv[1]) * cst[e] + sigf(gv[0]) * tanh_fast(gv[2]);
      cst[e] = cn;
      float hn = sigf(gv[3]) * tanh_fast(cn);
      // pack 4 neighboring h (hl..hl+3) into one u64 agent-relaxed store
      unsigned hb16 = (unsigned)(unsigned short)f2bf(hn);
      unsigned pair = hb16 | ((unsigned)__shfl_xor((int)hb16, 1, 64) << 16);
      unsigned long long v64 =
          (unsigned long long)pair |
          ((unsigned long long)(unsigned)__shfl_xor((int)pair, 2, 64) << 32);
      if ((hl & 3) == 0)
        __hip_atomic_store(&nxt64[(size_t)b * 128 + w * 4 + (hl >> 2)], v64,
                           __ATOMIC_RELAXED, __HIP_MEMORY_SCOPE_AGENT);
    }
    __syncthreads();  // every wave: s_waitcnt vmcnt(0) -> all stores acked at IC

    // ---- group barrier: relaxed monotonic flags (no inv/wb instructions) ----
    if (tid == 0)
      __hip_atomic_store(&fl[w], t + 1, __ATOMIC_RELAXED, __HIP_MEMORY_SCOPE_AGENT);
    // out[t-1] AFTER the flag release: member 0 no longer delays its group
    if (w == 0 && t > 0 && tid < MROWS * NO) {
      int b = tid / NO, o = tid - b * NO;
      float bo = (o == 0) ? bfc0 : (o == 1) ? bfc1 : bfc2;
      out[((size_t)(g * MROWS + b) * NTT + (t - 1)) * NO + o] =
          bo + fcbuf[0][b][o] + fcbuf[1][b][o] + fcbuf[2][b][o] + fcbuf[3][b][o];
    }
    if (tid < MEMBERS) {
      while (__hip_atomic_load(&fl[tid], __ATOMIC_RELAXED, __HIP_MEMORY_SCOPE_AGENT) < t + 1)
        __builtin_amdgcn_s_sleep(1);
    }
    __syncthreads();

    // ---- read group's h_{t+1} slab (32 KB) from IC -> LDS ----
    const unsigned long long* src =
        (const unsigned long long*)(((t & 1) ? buf1 : buf0) + (size_t)g * (MROWS * NH));
#pragma unroll
    for (int j = 0; j < 16; ++j) {
      int idx = tid + 256 * j;  // 4096 u64 = 32 rows x 128
      unsigned long long v =
          __hip_atomic_load(src + idx, __ATOMIC_RELAXED, __HIP_MEMORY_SCOPE_AGENT);
      *(unsigned long long*)&hbuf[idx >> 7][(idx & 127) * 4] = v;
    }
    __syncthreads();
    ++tmod; if (tmod == hor) tmod = 0;
  }
}

extern "C" void kernel_launch(void* const* d_in, const int* in_sizes, int n_in,
                              void* d_out, int out_size, void* d_ws, size_t ws_size,
                              hipStream_t stream) {
  (void)in_sizes; (void)n_in; (void)out_size; (void)ws_size;
  const float* x    = (const float*)d_in[0];
  const float* W_ih = (const float*)d_in[1];
  const float* W_hh = (const float*)d_in[2];
  const float* b_ih = (const float*)d_in[3];
  const float* b_hh = (const float*)d_in[4];
  const float* W_fc = (const float*)d_in[5];
  const float* b_fc = (const float*)d_in[6];
  const int*   hor  = (const int*)d_in[7];
  lstm_kernel<<<dim3(256), dim3(256), 0, stream>>>(
      x, W_ih, W_hh, b_ih, b_hh, W_fc, b_fc, hor,
      (float*)d_out, (unsigned short*)d_ws);
}

// Round 7
// 3200.645 us; speedup vs baseline: 5.6881x; 1.2935x over previous
//
#include <hip/hip_runtime.h>

typedef __attribute__((ext_vector_type(8))) short bf16x8;   // 8 bf16 in 4 VGPRs
typedef __attribute__((ext_vector_type(4))) float f32x4;

#define NTT 512
#define NH  512
#define NIN 9
#define NO  3
#define MEMBERS 32    // WGs per group
#define MROWS   32    // batch rows per group
#define HPW     16    // hidden units per WG

__device__ __forceinline__ short f2bf(float f) {  // RNE fp32 -> bf16
  unsigned u = __builtin_bit_cast(unsigned, f);
  u = (u + 0x7fffu + ((u >> 16) & 1u)) >> 16;
  return (short)u;
}
__device__ __forceinline__ float bf2f(short s) {
  unsigned u = ((unsigned)(unsigned short)s) << 16;
  return __builtin_bit_cast(float, u);
}
__device__ __forceinline__ float sigf(float x) { return 1.f / (1.f + __expf(-x)); }
__device__ __forceinline__ float tanh_fast(float x) { return 1.f - 2.f / (1.f + __expf(2.f * x)); }

// ============================ TAGGED kernel =================================
// 256 WGs = 8 groups (32 batch rows) x 32 members (16 hidden each).
// h exchange: each h stored as u32 = bf16(h) | ((t+1)<<16). Tag+payload share
// one relaxed agent-scope store -> no producer drain, no flags. Consumers
// read the slab and retry until all tags == t+1 (word self-validates).
// Skew < 2 steps (full-slab read gates each step), so double-buffered slots
// never show a future tag; 0xAA poison (tag 0xAAAA) never matches t+1<=512.
__global__ __launch_bounds__(256, 1) void lstm_tagged(
    const float* __restrict__ x, const float* __restrict__ W_ih,
    const float* __restrict__ W_hh, const float* __restrict__ b_ih,
    const float* __restrict__ b_hh, const float* __restrict__ W_fc,
    const float* __restrict__ b_fc, const int* __restrict__ horizon,
    float* __restrict__ out, unsigned* __restrict__ ws32) {
  const int tid  = threadIdx.x;
  const int bid  = blockIdx.x;
  const int g    = bid >> 5;   // group: batch rows [32g, 32g+32)
  const int w    = bid & 31;   // member: hidden [16w, 16w+16)
  const int wid  = tid >> 6;   // wave = gate index (i,f,g,o)
  const int lane = tid & 63;
  const int l15  = lane & 15;
  const int quad = lane >> 4;
  const int hl   = tid & 15;   // update mapping: hidden-local
  const int b0   = tid >> 4;   // update mapping: rows b0, b0+16
  const int hg   = w * HPW + hl;

  // ws (u32): tagged h dbuf [2][8 grp][32 rows][512] = 2 x 512 KB
  unsigned* tbuf0 = ws32;
  unsigned* tbuf1 = ws32 + 131072;

  __shared__ __align__(16) unsigned short hbuf[32][520];  // 1040B rows, b128-aligned
  __shared__ __align__(16) float gbuf[4][16][36];         // [gate][hl][b] 144B stride
  __shared__ float fcbuf[4][32][4];                       // [wave(K-split)][b][o]
  __shared__ float xbuf[32][NIN];
  __shared__ float xw[64][NIN];                           // W_ih rows (gate*16+hl)
  __shared__ float bsl[64];

  // ---- persistent B fragments: W_hh hi/lo (fp32-exact weights) ----
  bf16x8 Bhi[16], Blo[16];
#pragma unroll
  for (int kt = 0; kt < 16; ++kt) {
    bf16x8 vh, vl;
    const int row = wid * NH + w * HPW + l15;
#pragma unroll
    for (int j = 0; j < 8; ++j) {
      int k = kt * 32 + quad * 8 + j;
      float v = W_hh[(size_t)row * NH + k];
      short hi = f2bf(v);
      vh[j] = hi; vl[j] = f2bf(v - bf2f(hi));
    }
    Bhi[kt] = vh; Blo[kt] = vl;
  }
  // fc tile: wave wid covers K quarter [128*wid, +128)
  bf16x8 Fhi[4], Flo[4];
#pragma unroll
  for (int kk = 0; kk < 4; ++kk) {
    bf16x8 vh, vl;
#pragma unroll
    for (int j = 0; j < 8; ++j) {
      int k = (wid * 4 + kk) * 32 + quad * 8 + j;
      float v = (l15 < NO) ? W_fc[(size_t)l15 * NH + k] : 0.f;
      short hi = f2bf(v);
      vh[j] = hi; vl[j] = f2bf(v - bf2f(hi));
    }
    Fhi[kk] = vh; Flo[kk] = vl;
  }
  if (tid < 64) {  // x-path weights + biases, fp32 exact, in LDS
    int grow = (tid >> 4) * NH + w * HPW + (tid & 15);
    bsl[tid] = b_ih[grow] + b_hh[grow];
#pragma unroll
    for (int k = 0; k < NIN; ++k) xw[tid][k] = W_ih[grow * NIN + k];
  }
  for (int i = tid; i < 8320; i += 256) ((unsigned*)hbuf)[i] = 0u;  // h_0 = 0
  const float bfc0 = b_fc[0], bfc1 = b_fc[1], bfc2 = b_fc[2];
  const int hor = *horizon;
  __syncthreads();

  float cst[2] = {0.f, 0.f};
  int tmod = 0;

  for (int t = 0; t <= NTT; ++t) {
    // x_t slice: issue global loads NOW (regs), write LDS after MFMA.
    float xv0 = 0.f, xv1 = 0.f;
    int r0 = 0, k0 = 0, r1 = 0, k1 = 0;
    if (t < NTT) {
      r0 = tid / NIN; k0 = tid - r0 * NIN;
      if (r0 < MROWS) xv0 = x[((size_t)(g * MROWS + r0) * NTT + t) * NIN + k0];
      int i1 = tid + 256;
      r1 = i1 / NIN; k1 = i1 - r1 * NIN;
      if (i1 < MROWS * NIN) xv1 = x[((size_t)(g * MROWS + r1) * NTT + t) * NIN + k1];
    }

    // ---- MFMA: this gate's 16 cols over full K, both M-tiles; fc K-quarter ----
    f32x4 z4 = {0.f, 0.f, 0.f, 0.f};
    f32x4 accg[2] = {z4, z4}, accf[2] = {z4, z4};
#pragma unroll
    for (int kt = 0; kt < 16; ++kt) {
      bf16x8 a0 = *(const bf16x8*)&hbuf[l15][kt * 32 + quad * 8];
      bf16x8 a1 = *(const bf16x8*)&hbuf[16 + l15][kt * 32 + quad * 8];
      accg[0] = __builtin_amdgcn_mfma_f32_16x16x32_bf16(a0, Bhi[kt], accg[0], 0, 0, 0);
      accg[1] = __builtin_amdgcn_mfma_f32_16x16x32_bf16(a1, Bhi[kt], accg[1], 0, 0, 0);
      accg[0] = __builtin_amdgcn_mfma_f32_16x16x32_bf16(a0, Blo[kt], accg[0], 0, 0, 0);
      accg[1] = __builtin_amdgcn_mfma_f32_16x16x32_bf16(a1, Blo[kt], accg[1], 0, 0, 0);
      if ((kt >> 2) == wid) {
        int kk = kt & 3;
        accf[0] = __builtin_amdgcn_mfma_f32_16x16x32_bf16(a0, Fhi[kk], accf[0], 0, 0, 0);
        accf[1] = __builtin_amdgcn_mfma_f32_16x16x32_bf16(a1, Fhi[kk], accf[1], 0, 0, 0);
        accf[0] = __builtin_amdgcn_mfma_f32_16x16x32_bf16(a0, Flo[kk], accf[0], 0, 0, 0);
        accf[1] = __builtin_amdgcn_mfma_f32_16x16x32_bf16(a1, Flo[kk], accf[1], 0, 0, 0);
      }
    }
    // stage: D row(b) = mt*16 + quad*4 + r, col = l15
#pragma unroll
    for (int mt = 0; mt < 2; ++mt)
      *(f32x4*)&gbuf[wid][l15][mt * 16 + quad * 4] = accg[mt];
    if (l15 < NO) {
#pragma unroll
      for (int mt = 0; mt < 2; ++mt)
#pragma unroll
        for (int r = 0; r < 4; ++r) fcbuf[wid][mt * 16 + quad * 4 + r][l15] = accf[mt][r];
    }
    if (t < NTT) {
      if (r0 < MROWS) xbuf[r0][k0] = xv0;
      if (tid < MROWS * NIN - 256) xbuf[r1][k1] = xv1;
    }
    __syncthreads();

    if (t == NTT) {  // final fc only
      if (w == 0 && tid < MROWS * NO) {
        int b = tid / NO, o = tid - b * NO;
        float bo = (o == 0) ? bfc0 : (o == 1) ? bfc1 : bfc2;
        out[((size_t)(g * MROWS + b) * NTT + (t - 1)) * NO + o] =
            bo + fcbuf[0][b][o] + fcbuf[1][b][o] + fcbuf[2][b][o] + fcbuf[3][b][o];
      }
      break;
    }

    const bool raw = (t < 5) || (tmod == 0);
    const unsigned tg = (unsigned)(t + 1);
    unsigned* dst = ((t & 1) ? tbuf1 : tbuf0) + (size_t)g * 16384;  // u32 slab

    // ---- cell update: thread owns (b0, hl) and (b0+16, hl) ----
#pragma unroll
    for (int e = 0; e < 2; ++e) {
      int b = b0 + 16 * e;
      float xin[NIN];
#pragma unroll
      for (int k = 0; k < NIN; ++k) xin[k] = xbuf[b][k];
      if (!raw) {
        xin[0] = bfc0 + fcbuf[0][b][0] + fcbuf[1][b][0] + fcbuf[2][b][0] + fcbuf[3][b][0];
        xin[1] = bfc1 + fcbuf[0][b][1] + fcbuf[1][b][1] + fcbuf[2][b][1] + fcbuf[3][b][1];
        xin[2] = bfc2 + fcbuf[0][b][2] + fcbuf[1][b][2] + fcbuf[2][b][2] + fcbuf[3][b][2];
      }
      float gv[4];
#pragma unroll
      for (int gg = 0; gg < 4; ++gg) {
        int r = gg * 16 + hl;
        float s = bsl[r] + gbuf[gg][hl][b];
#pragma unroll
        for (int k = 0; k < NIN; ++k) s += xin[k] * xw[r][k];
        gv[gg] = s;
      }
      float cn = sigf(gv[1]) * cst[e] + sigf(gv[0]) * tanh_fast(gv[2]);
      cst[e] = cn;
      float hn = sigf(gv[3]) * tanh_fast(cn);
      // tagged store: payload+tag in ONE u32 -> atomic consistency for free
      unsigned word = (unsigned)(unsigned short)f2bf(hn) | (tg << 16);
      __hip_atomic_store(&dst[(size_t)b * NH + hg], word,
                         __ATOMIC_RELAXED, __HIP_MEMORY_SCOPE_AGENT);
    }

    // out[t-1]: member 0 writes (off the exchange critical path)
    if (w == 0 && t > 0 && tid < MROWS * NO) {
      int b = tid / NO, o = tid - b * NO;
      float bo = (o == 0) ? bfc0 : (o == 1) ? bfc1 : bfc2;
      out[((size_t)(g * MROWS + b) * NTT + (t - 1)) * NO + o] =
          bo + fcbuf[0][b][o] + fcbuf[1][b][o] + fcbuf[2][b][o] + fcbuf[3][b][o];
    }

    // ---- exchange: poll tagged slab until all 16384 words carry tag t+1 ----
    // u64 q covers u32 pair (2q,2q+1): row = q>>8, u32-in-row = q&255.
    {
      const unsigned long long* src =
          (const unsigned long long*)(((t & 1) ? tbuf1 : tbuf0) + (size_t)g * 16384);
      const unsigned long long pat =
          ((unsigned long long)tg << 16) | ((unsigned long long)tg << 48);
      unsigned* hb32 = (unsigned*)hbuf;
      for (;;) {
        unsigned long long bad = 0;
#pragma unroll
        for (int bb = 0; bb < 4; ++bb) {
          unsigned long long v[8];
#pragma unroll
          for (int j = 0; j < 8; ++j)
            v[j] = __hip_atomic_load(src + tid + 256 * (bb * 8 + j),
                                     __ATOMIC_RELAXED, __HIP_MEMORY_SCOPE_AGENT);
#pragma unroll
          for (int j = 0; j < 8; ++j) {
            int q = tid + 256 * (bb * 8 + j);
            bad |= (v[j] ^ pat) & 0xFFFF0000FFFF0000ULL;
            unsigned pk = (unsigned)(v[j] & 0xFFFFu) |
                          ((unsigned)(v[j] >> 32) << 16);
            hb32[(q >> 8) * 260 + (q & 255)] = pk;  // optimistic; rewritten on retry
          }
        }
        if (__syncthreads_count(bad != 0) == 0) break;  // also the LDS barrier
        __builtin_amdgcn_s_sleep(1);
      }
    }
    ++tmod; if (tmod == hor) tmod = 0;
  }
}

// ====================== FALLBACK kernel (r4 verbatim) =======================
__global__ __launch_bounds__(256, 1) void lstm_fallback(
    const float* __restrict__ x, const float* __restrict__ W_ih,
    const float* __restrict__ W_hh, const float* __restrict__ b_ih,
    const float* __restrict__ b_hh, const float* __restrict__ W_fc,
    const float* __restrict__ b_fc, const int* __restrict__ horizon,
    float* __restrict__ out, unsigned short* __restrict__ ws) {
  const int tid  = threadIdx.x;
  const int bid  = blockIdx.x;
  const int g    = bid >> 5;
  const int w    = bid & 31;
  const int wid  = tid >> 6;
  const int lane = tid & 63;
  const int l15  = lane & 15;
  const int quad = lane >> 4;
  const int hl   = tid & 15;
  const int b0   = tid >> 4;

  unsigned short* buf0 = ws;
  unsigned short* buf1 = ws + 131072;
  int* fl = (int*)(ws + 262144) + g * MEMBERS;

  __shared__ __align__(16) unsigned short hbuf[32][520];
  __shared__ __align__(16) float gbuf[4][16][36];
  __shared__ float fcbuf[4][32][4];
  __shared__ float xbuf[32][NIN];
  __shared__ float xw[64][NIN];
  __shared__ float bsl[64];

  bf16x8 Bhi[16], Blo[16];
#pragma unroll
  for (int kt = 0; kt < 16; ++kt) {
    bf16x8 vh, vl;
    const int row = wid * NH + w * HPW + l15;
#pragma unroll
    for (int j = 0; j < 8; ++j) {
      int k = kt * 32 + quad * 8 + j;
      float v = W_hh[(size_t)row * NH + k];
      short hi = f2bf(v);
      vh[j] = hi; vl[j] = f2bf(v - bf2f(hi));
    }
    Bhi[kt] = vh; Blo[kt] = vl;
  }
  bf16x8 Fhi[4], Flo[4];
#pragma unroll
  for (int kk = 0; kk < 4; ++kk) {
    bf16x8 vh, vl;
#pragma unroll
    for (int j = 0; j < 8; ++j) {
      int k = (wid * 4 + kk) * 32 + quad * 8 + j;
      float v = (l15 < NO) ? W_fc[(size_t)l15 * NH + k] : 0.f;
      short hi = f2bf(v);
      vh[j] = hi; vl[j] = f2bf(v - bf2f(hi));
    }
    Fhi[kk] = vh; Flo[kk] = vl;
  }
  if (tid < 64) {
    int grow = (tid >> 4) * NH + w * HPW + (tid & 15);
    bsl[tid] = b_ih[grow] + b_hh[grow];
#pragma unroll
    for (int k = 0; k < NIN; ++k) xw[tid][k] = W_ih[grow * NIN + k];
  }
  for (int i = tid; i < 8320; i += 256) ((unsigned*)hbuf)[i] = 0u;
  const float bfc0 = b_fc[0], bfc1 = b_fc[1], bfc2 = b_fc[2];
  const int hor = *horizon;
  __syncthreads();

  float cst[2] = {0.f, 0.f};
  int tmod = 0;

  for (int t = 0; t <= NTT; ++t) {
    float xv0 = 0.f, xv1 = 0.f;
    int r0 = 0, k0 = 0, r1 = 0, k1 = 0;
    if (t < NTT) {
      r0 = tid / NIN; k0 = tid - r0 * NIN;
      if (r0 < MROWS) xv0 = x[((size_t)(g * MROWS + r0) * NTT + t) * NIN + k0];
      int i1 = tid + 256;
      r1 = i1 / NIN; k1 = i1 - r1 * NIN;
      if (i1 < MROWS * NIN) xv1 = x[((size_t)(g * MROWS + r1) * NTT + t) * NIN + k1];
    }
    f32x4 z4 = {0.f, 0.f, 0.f, 0.f};
    f32x4 accg[2] = {z4, z4}, accf[2] = {z4, z4};
#pragma unroll
    for (int kt = 0; kt < 16; ++kt) {
      bf16x8 a0 = *(const bf16x8*)&hbuf[l15][kt * 32 + quad * 8];
      bf16x8 a1 = *(const bf16x8*)&hbuf[16 + l15][kt * 32 + quad * 8];
      accg[0] = __builtin_amdgcn_mfma_f32_16x16x32_bf16(a0, Bhi[kt], accg[0], 0, 0, 0);
      accg[1] = __builtin_amdgcn_mfma_f32_16x16x32_bf16(a1, Bhi[kt], accg[1], 0, 0, 0);
      accg[0] = __builtin_amdgcn_mfma_f32_16x16x32_bf16(a0, Blo[kt], accg[0], 0, 0, 0);
      accg[1] = __builtin_amdgcn_mfma_f32_16x16x32_bf16(a1, Blo[kt], accg[1], 0, 0, 0);
      if ((kt >> 2) == wid) {
        int kk = kt & 3;
        accf[0] = __builtin_amdgcn_mfma_f32_16x16x32_bf16(a0, Fhi[kk], accf[0], 0, 0, 0);
        accf[1] = __builtin_amdgcn_mfma_f32_16x16x32_bf16(a1, Fhi[kk], accf[1], 0, 0, 0);
        accf[0] = __builtin_amdgcn_mfma_f32_16x16x32_bf16(a0, Flo[kk], accf[0], 0, 0, 0);
        accf[1] = __builtin_amdgcn_mfma_f32_16x16x32_bf16(a1, Flo[kk], accf[1], 0, 0, 0);
      }
    }
#pragma unroll
    for (int mt = 0; mt < 2; ++mt)
      *(f32x4*)&gbuf[wid][l15][mt * 16 + quad * 4] = accg[mt];
    if (l15 < NO) {
#pragma unroll
      for (int mt = 0; mt < 2; ++mt)
#pragma unroll
        for (int r = 0; r < 4; ++r) fcbuf[wid][mt * 16 + quad * 4 + r][l15] = accf[mt][r];
    }
    if (t < NTT) {
      if (r0 < MROWS) xbuf[r0][k0] = xv0;
      if (tid < MROWS * NIN - 256) xbuf[r1][k1] = xv1;
    }
    __syncthreads();

    if (t == NTT) {
      if (w == 0 && tid < MROWS * NO) {
        int b = tid / NO, o = tid - b * NO;
        float bo = (o == 0) ? bfc0 : (o == 1) ? bfc1 : bfc2;
        out[((size_t)(g * MROWS + b) * NTT + (t - 1)) * NO + o] =
            bo + fcbuf[0][b][o] + fcbuf[1][b][o] + fcbuf[2][b][o] + fcbuf[3][b][o];
      }
      break;
    }

    const bool raw = (t < 5) || (tmod == 0);
    unsigned long long* nxt64 =
        (unsigned long long*)(((t & 1) ? buf1 : buf0) + (size_t)g * (MROWS * NH));
#pragma unroll
    for (int e = 0; e < 2; ++e) {
      int b = b0 + 16 * e;
      float xin[NIN];
#pragma unroll
      for (int k = 0; k < NIN; ++k) xin[k] = xbuf[b][k];
      if (!raw) {
        xin[0] = bfc0 + fcbuf[0][b][0] + fcbuf[1][b][0] + fcbuf[2][b][0] + fcbuf[3][b][0];
        xin[1] = bfc1 + fcbuf[0][b][1] + fcbuf[1][b][1] + fcbuf[2][b][1] + fcbuf[3][b][1];
        xin[2] = bfc2 + fcbuf[0][b][2] + fcbuf[1][b][2] + fcbuf[2][b][2] + fcbuf[3][b][2];
      }
      float gv[4];
#pragma unroll
      for (int gg = 0; gg < 4; ++gg) {
        int r = gg * 16 + hl;
        float s = bsl[r] + gbuf[gg][hl][b];
#pragma unroll
        for (int k = 0; k < NIN; ++k) s += xin[k] * xw[r][k];
        gv[gg] = s;
      }
      float cn = sigf(gv[1]) * cst[e] + sigf(gv[0]) * tanh_fast(gv[2]);
      cst[e] = cn;
      float hn = sigf(gv[3]) * tanh_fast(cn);
      unsigned hb16 = (unsigned)(unsigned short)f2bf(hn);
      unsigned pair = hb16 | ((unsigned)__shfl_xor((int)hb16, 1, 64) << 16);
      unsigned long long v64 =
          (unsigned long long)pair |
          ((unsigned long long)(unsigned)__shfl_xor((int)pair, 2, 64) << 32);
      if ((hl & 3) == 0)
        __hip_atomic_store(&nxt64[(size_t)b * 128 + w * 4 + (hl >> 2)], v64,
                           __ATOMIC_RELAXED, __HIP_MEMORY_SCOPE_AGENT);
    }
    asm volatile("s_waitcnt vmcnt(0)" ::: "memory");
    __syncthreads();

    if (tid == 0)
      __hip_atomic_store(&fl[w], t + 1, __ATOMIC_RELAXED, __HIP_MEMORY_SCOPE_AGENT);
    if (w == 0 && t > 0 && tid < MROWS * NO) {
      int b = tid / NO, o = tid - b * NO;
      float bo = (o == 0) ? bfc0 : (o == 1) ? bfc1 : bfc2;
      out[((size_t)(g * MROWS + b) * NTT + (t - 1)) * NO + o] =
          bo + fcbuf[0][b][o] + fcbuf[1][b][o] + fcbuf[2][b][o] + fcbuf[3][b][o];
    }
    if (tid < MEMBERS) {
      while (__hip_atomic_load(&fl[tid], __ATOMIC_RELAXED,
                               __HIP_MEMORY_SCOPE_AGENT) < t + 1)
        __builtin_amdgcn_s_sleep(1);
    }
    __syncthreads();

    const unsigned long long* src =
        (const unsigned long long*)(((t & 1) ? buf1 : buf0) + (size_t)g * (MROWS * NH));
#pragma unroll
    for (int j = 0; j < 16; ++j) {
      int idx = tid + 256 * j;
      unsigned long long v =
          __hip_atomic_load(src + idx, __ATOMIC_RELAXED, __HIP_MEMORY_SCOPE_AGENT);
      *(unsigned long long*)&hbuf[idx >> 7][(idx & 127) * 4] = v;
    }
    __syncthreads();
    ++tmod; if (tmod == hor) tmod = 0;
  }
}

extern "C" void kernel_launch(void* const* d_in, const int* in_sizes, int n_in,
                              void* d_out, int out_size, void* d_ws, size_t ws_size,
                              hipStream_t stream) {
  (void)in_sizes; (void)n_in; (void)out_size;
  const float* x    = (const float*)d_in[0];
  const float* W_ih = (const float*)d_in[1];
  const float* W_hh = (const float*)d_in[2];
  const float* b_ih = (const float*)d_in[3];
  const float* b_hh = (const float*)d_in[4];
  const float* W_fc = (const float*)d_in[5];
  const float* b_fc = (const float*)d_in[6];
  const int*   hor  = (const int*)d_in[7];
  if (ws_size >= (size_t)1048576) {
    lstm_tagged<<<dim3(256), dim3(256), 0, stream>>>(
        x, W_ih, W_hh, b_ih, b_hh, W_fc, b_fc, hor,
        (float*)d_out, (unsigned*)d_ws);
  } else {
    lstm_fallback<<<dim3(256), dim3(256), 0, stream>>>(
        x, W_ih, W_hh, b_ih, b_hh, W_fc, b_fc, hor,
        (float*)d_out, (unsigned short*)d_ws);
  }
}